// Round 1
// baseline (274.083 us; speedup 1.0000x reference)
//
#include <hip/hip_runtime.h>
#include <math.h>

static constexpr int B = 32, H = 256, N = 512, T = 2048;
static constexpr int TT = 32;   // t-tile per block
static constexpr int KC = 32;   // n-chunk
static constexpr float kLOG_2PI = 1.8378770664093453f;
static constexpr float kLOG2E   = 1.4426950408889634f;
static constexpr float kNEG_BIG = -3.0e38f;

// Kernel 1: per-batch centers c[n] = cumsum(d) - 0.5*d, plus folded Gaussian
// coefficients in base-2: w2(n,t) = a2[n] - q2[n]*(t-c[n])^2   (w2 = w*log2e)
__global__ void k_prep(const float* __restrict__ dur, const float* __restrict__ vars,
                       float* __restrict__ c, float* __restrict__ a2, float* __restrict__ q2) {
  const int b = blockIdx.x;
  const int lane = threadIdx.x;  // 64
  float running = 0.f;
  for (int i = 0; i < N / 64; ++i) {
    const int n = i * 64 + lane;
    const float d = dur[b * N + n];
    float x = d;
#pragma unroll
    for (int off = 1; off < 64; off <<= 1) {
      float up = __shfl_up(x, off, 64);
      if (lane >= off) x += up;
    }
    const float cc = running + x - 0.5f * d;   // uses pre-chunk running sum
    running += __shfl(x, 63, 64);
    const float v = vars[b * N + n];
    c[b * N + n]  = cc;
    a2[b * N + n] = -0.5f * (kLOG_2PI + logf(v)) * kLOG2E;
    q2[b * N + n] = 0.5f * kLOG2E / v;
  }
}

// Kernel 2: per-(b,t) softmax max m2 and inv-sum (base-2 domain). One wave per (b,t).
__global__ void k_ms(const float* __restrict__ c, const float* __restrict__ a2,
                     const float* __restrict__ q2, const int* __restrict__ lens,
                     float2* __restrict__ ms) {
  const int wid = (blockIdx.x * blockDim.x + threadIdx.x) >> 6;
  const int lane = threadIdx.x & 63;
  const int b = wid >> 11;          // T = 2048
  const int t = wid & (T - 1);
  const int L = lens[b];
  const float tf = (float)t;
  float w[N / 64];
  float m = kNEG_BIG;
#pragma unroll
  for (int i = 0; i < N / 64; ++i) {
    const int n = i * 64 + lane;
    const float cc = c[b * N + n];
    const float tc = tf - cc;
    float ww = fmaf(-q2[b * N + n], tc * tc, a2[b * N + n]);
    ww = (n < L) ? ww : kNEG_BIG;
    w[i] = ww;
    m = fmaxf(m, ww);
  }
#pragma unroll
  for (int off = 32; off; off >>= 1) m = fmaxf(m, __shfl_xor(m, off, 64));
  float s = 0.f;
#pragma unroll
  for (int i = 0; i < N / 64; ++i) s += exp2f(w[i] - m);  // masked: exp2(-3e38)=0
#pragma unroll
  for (int off = 32; off; off >>= 1) s += __shfl_xor(s, off, 64);
  if (lane == 0) ms[b * T + t] = make_float2(m, 1.0f / s);
}

// Kernel 3: out[b,h,t0+t] = sum_n p(b,n,t) * enc[b,h,n], p computed on the fly.
// Block: 256 threads, tile = 256 h x 32 t. Thread: 4 h x 8 t register tile.
__global__ __launch_bounds__(256) void k_gemm(
    const float* __restrict__ enc, const float* __restrict__ c,
    const float* __restrict__ a2, const float* __restrict__ q2,
    const int* __restrict__ lens, const float2* __restrict__ ms,
    float* __restrict__ out) {
  __shared__ float e_lds[H][33];      // [h][k], pad 33 -> conflict-free column reads
  __shared__ float p_lds[KC][TT];     // [k][t]
  __shared__ float m_lds[TT];
  __shared__ float is_lds[TT];

  const int b = blockIdx.y;
  const int t0 = blockIdx.x * TT;
  const int tid = threadIdx.x;
  const int lane_h = tid & 63;
  const int sub = tid >> 6;     // 0..3 (uniform per wave)
  const int tsub = sub * 8;
  const int L = lens[b];
  const float* encb = enc + (size_t)b * H * N;

  if (tid < TT) {
    const float2 v = ms[b * T + t0 + tid];
    m_lds[tid] = v.x;
    is_lds[tid] = v.y;
  }

  float acc[4][8];
#pragma unroll
  for (int j = 0; j < 4; ++j)
#pragma unroll
    for (int i = 0; i < 8; ++i) acc[j][i] = 0.f;

  for (int n0 = 0; n0 < N; n0 += KC) {
    __syncthreads();  // previous compute done (and covers m_lds init on iter 0)
    // stage enc chunk (coalesced): 256 rows x 32 floats = 32 KB
#pragma unroll
    for (int i = 0; i < 8; ++i) {
      const int idx = tid + 256 * i;   // 0..2047 float4s
      const int h = idx >> 3;
      const int f4 = idx & 7;
      const float4 v = *(const float4*)(encb + h * N + n0 + f4 * 4);
      float* dst = &e_lds[h][f4 * 4];
      dst[0] = v.x; dst[1] = v.y; dst[2] = v.z; dst[3] = v.w;
    }
    // compute p chunk: 32 k x 32 t
#pragma unroll
    for (int i = 0; i < 4; ++i) {
      const int idx = tid + 256 * i;   // 0..1023
      const int k = idx >> 5;
      const int t = idx & 31;
      const int n = n0 + k;
      const float cc = c[b * N + n];
      const float tf = (float)(t0 + t);
      const float tc = tf - cc;
      const float w2 = fmaf(-q2[b * N + n], tc * tc, a2[b * N + n]);
      const float p = (n < L) ? exp2f(w2 - m_lds[t]) * is_lds[t] : 0.f;
      p_lds[k][t] = p;
    }
    __syncthreads();
    // multiply-accumulate
#pragma unroll
    for (int k = 0; k < KC; ++k) {
      const float4 pa = *(const float4*)&p_lds[k][tsub];
      const float4 pb = *(const float4*)&p_lds[k][tsub + 4];
      const float pv[8] = {pa.x, pa.y, pa.z, pa.w, pb.x, pb.y, pb.z, pb.w};
#pragma unroll
      for (int j = 0; j < 4; ++j) {
        const float e = e_lds[lane_h + 64 * j][k];
#pragma unroll
        for (int i = 0; i < 8; ++i) acc[j][i] = fmaf(e, pv[i], acc[j][i]);
      }
    }
  }

#pragma unroll
  for (int j = 0; j < 4; ++j) {
    const int h = lane_h + 64 * j;
    float* o = out + ((size_t)(b * H + h)) * T + t0 + tsub;
    *(float4*)(o)     = make_float4(acc[j][0], acc[j][1], acc[j][2], acc[j][3]);
    *(float4*)(o + 4) = make_float4(acc[j][4], acc[j][5], acc[j][6], acc[j][7]);
  }
}

extern "C" void kernel_launch(void* const* d_in, const int* in_sizes, int n_in,
                              void* d_out, int out_size, void* d_ws, size_t ws_size,
                              hipStream_t stream) {
  const float* enc  = (const float*)d_in[0];
  const float* dur  = (const float*)d_in[1];
  const float* vars = (const float*)d_in[2];
  const int*   lens = (const int*)d_in[3];
  float* out = (float*)d_out;

  float*  cbuf  = (float*)d_ws;            // B*N
  float*  a2buf = cbuf + B * N;            // B*N
  float*  q2buf = a2buf + B * N;           // B*N
  float2* msbuf = (float2*)(q2buf + B * N);  // B*T float2  (total ~704 KB)

  k_prep<<<B, 64, 0, stream>>>(dur, vars, cbuf, a2buf, q2buf);
  k_ms<<<(B * T) / 4, 256, 0, stream>>>(cbuf, a2buf, q2buf, lens, msbuf);
  k_gemm<<<dim3(T / TT, B), 256, 0, stream>>>(enc, cbuf, a2buf, q2buf, lens, msbuf, out);
}

// Round 2
// 107.220 us; speedup vs baseline: 2.5563x; 2.5563x over previous
//
#include <hip/hip_runtime.h>
#include <math.h>

static constexpr int B = 32, H = 256, N = 512, T = 2048;
static constexpr int TTILE = 64;  // t-tile per gemm block
static constexpr int KC = 64;     // n-chunk
static constexpr float kLOG_2PI = 1.8378770664093453f;
static constexpr float kLOG2E   = 1.4426950408889634f;
static constexpr float kNEG_BIG = -3.0e38f;

typedef __attribute__((ext_vector_type(8))) short bf16x8;
typedef __attribute__((ext_vector_type(4))) float f32x4;

static __device__ __forceinline__ short f2bf(float f) {
  unsigned u = __float_as_uint(f);
  unsigned r = (u + 0x7fffu + ((u >> 16) & 1u)) >> 16;   // RNE
  return (short)r;
}

// Kernel 1: per-batch centers c[n] = cumsum(d) - 0.5*d, plus folded Gaussian
// coefficients in base-2: w2(n,t) = a2[n] - q2[n]*(t-c[n])^2   (w2 = w*log2e)
__global__ void k_prep(const float* __restrict__ dur, const float* __restrict__ vars,
                       float* __restrict__ c, float* __restrict__ a2, float* __restrict__ q2) {
  const int b = blockIdx.x;
  const int lane = threadIdx.x;  // 64
  float running = 0.f;
  for (int i = 0; i < N / 64; ++i) {
    const int n = i * 64 + lane;
    const float d = dur[b * N + n];
    float x = d;
#pragma unroll
    for (int off = 1; off < 64; off <<= 1) {
      float up = __shfl_up(x, off, 64);
      if (lane >= off) x += up;
    }
    const float cc = running + x - 0.5f * d;
    running += __shfl(x, 63, 64);
    const float v = vars[b * N + n];
    c[b * N + n]  = cc;
    a2[b * N + n] = -0.5f * (kLOG_2PI + logf(v)) * kLOG2E;
    q2[b * N + n] = 0.5f * kLOG2E / v;
  }
}

// Kernel 2: per-(b,t) softmax max m2 and inv-sum (base-2 domain). One wave per (b,t).
__global__ void k_ms(const float* __restrict__ c, const float* __restrict__ a2,
                     const float* __restrict__ q2, const int* __restrict__ lens,
                     float2* __restrict__ ms) {
  const int wid = (blockIdx.x * blockDim.x + threadIdx.x) >> 6;
  const int lane = threadIdx.x & 63;
  const int b = wid >> 11;          // T = 2048
  const int t = wid & (T - 1);
  const int L = lens[b];
  const float tf = (float)t;
  float w[N / 64];
  float m = kNEG_BIG;
#pragma unroll
  for (int i = 0; i < N / 64; ++i) {
    const int n = i * 64 + lane;
    const float cc = c[b * N + n];
    const float tc = tf - cc;
    float ww = fmaf(-q2[b * N + n], tc * tc, a2[b * N + n]);
    ww = (n < L) ? ww : kNEG_BIG;
    w[i] = ww;
    m = fmaxf(m, ww);
  }
#pragma unroll
  for (int off = 32; off; off >>= 1) m = fmaxf(m, __shfl_xor(m, off, 64));
  float s = 0.f;
#pragma unroll
  for (int i = 0; i < N / 64; ++i) s += exp2f(w[i] - m);  // masked: exp2(-3e38)=0
#pragma unroll
  for (int off = 32; off; off >>= 1) s += __shfl_xor(s, off, 64);
  if (lane == 0) ms[b * T + t] = make_float2(m, 1.0f / s);
}

// Kernel 3: out[b,h,t0+t] = sum_n p(b,n,t) * enc[b,h,n]  via bf16 MFMA.
// Block: 256 threads (4 waves), tile 256h x 64t, K-chunks of 64.
// Wave w owns rows [w*64, w*64+64), 4x4 fragments of 16x16, acc fp32.
__global__ __launch_bounds__(256) void k_gemm(
    const float* __restrict__ enc, const float* __restrict__ c,
    const float* __restrict__ a2, const float* __restrict__ q2,
    const int* __restrict__ lens, const float2* __restrict__ ms,
    float* __restrict__ out) {
  __shared__ short eA[H * KC];       // bf16, swizzled [h][k]
  __shared__ short pB[TTILE * KC];   // bf16, swizzled [t][k]
  __shared__ float cs[N], a2s[N], q2s[N];
  __shared__ float2 mss[TTILE];

  const int b = blockIdx.y;
  const int t0 = blockIdx.x * TTILE;
  const int tid = threadIdx.x;
  const int lane = tid & 63;
  const int wave = tid >> 6;
  const int L = lens[b];
  const float* encb = enc + (size_t)b * H * N;

  // stage per-batch params once
  for (int i = tid; i < N; i += 256) {
    cs[i]  = c[b * N + i];
    a2s[i] = a2[b * N + i];
    q2s[i] = q2[b * N + i];
  }
  if (tid < TTILE) mss[tid] = ms[b * T + t0 + tid];

  f32x4 acc[4][4];
#pragma unroll
  for (int mf = 0; mf < 4; ++mf)
#pragma unroll
    for (int tf = 0; tf < 4; ++tf) acc[mf][tf] = (f32x4){0.f, 0.f, 0.f, 0.f};

  const int l15 = lane & 15;
  const int lhi = lane >> 4;

  for (int n0 = 0; n0 < N; n0 += KC) {
    __syncthreads();   // prev chunk's MFMA reads done (iter 0: params staged)
    // stage A: 256h x 64k. 2048 16B-slots; thread handles 8 (load 8 fp32 -> bf16x8)
#pragma unroll
    for (int i = 0; i < 8; ++i) {
      const int flat = i * 256 + tid;          // = h*8 + j8
      const int h = flat >> 3, j8 = flat & 7;
      const float4 v0 = *(const float4*)(encb + h * N + n0 + j8 * 8);
      const float4 v1 = *(const float4*)(encb + h * N + n0 + j8 * 8 + 4);
      bf16x8 w;
      w[0] = f2bf(v0.x); w[1] = f2bf(v0.y); w[2] = f2bf(v0.z); w[3] = f2bf(v0.w);
      w[4] = f2bf(v1.x); w[5] = f2bf(v1.y); w[6] = f2bf(v1.z); w[7] = f2bf(v1.w);
      const int byte = ((h * KC + j8 * 8) * 2) ^ ((h & 7) << 4);
      *(bf16x8*)((char*)eA + byte) = w;
    }
    // stage B: p[t][k], 64x64. 512 slots; thread handles 2.
#pragma unroll
    for (int i = 0; i < 2; ++i) {
      const int flat = i * 256 + tid;          // = t*8 + j8
      const int t = flat >> 3, j8 = flat & 7;
      const float2 msv = mss[t];
      const float tf = (float)(t0 + t);
      bf16x8 w;
#pragma unroll
      for (int jj = 0; jj < 8; ++jj) {
        const int n = n0 + j8 * 8 + jj;
        const float tc = tf - cs[n];
        const float w2 = fmaf(-q2s[n], tc * tc, a2s[n]);
        const float pv = (n < L) ? exp2f(w2 - msv.x) * msv.y : 0.f;
        w[jj] = f2bf(pv);
      }
      const int byte = ((t * KC + j8 * 8) * 2) ^ ((t & 7) << 4);
      *(bf16x8*)((char*)pB + byte) = w;
    }
    __syncthreads();
    // MFMA: 2 k-steps of 32, 4x4 fragments
#pragma unroll
    for (int kk = 0; kk < KC; kk += 32) {
      bf16x8 aF[4], bF[4];
#pragma unroll
      for (int mf = 0; mf < 4; ++mf) {
        const int h = wave * 64 + mf * 16 + l15;
        const int byte = ((h * KC + kk + lhi * 8) * 2) ^ ((h & 7) << 4);
        aF[mf] = *(const bf16x8*)((const char*)eA + byte);
      }
#pragma unroll
      for (int tf = 0; tf < 4; ++tf) {
        const int t = tf * 16 + l15;
        const int byte = ((t * KC + kk + lhi * 8) * 2) ^ ((t & 7) << 4);
        bF[tf] = *(const bf16x8*)((const char*)pB + byte);
      }
#pragma unroll
      for (int mf = 0; mf < 4; ++mf)
#pragma unroll
        for (int tf = 0; tf < 4; ++tf)
          acc[mf][tf] = __builtin_amdgcn_mfma_f32_16x16x32_bf16(aF[mf], bF[tf], acc[mf][tf], 0, 0, 0);
    }
  }

  // epilogue: C/D layout col=lane&15 (t), row=(lane>>4)*4+r (h)
#pragma unroll
  for (int mf = 0; mf < 4; ++mf) {
#pragma unroll
    for (int tf = 0; tf < 4; ++tf) {
#pragma unroll
      for (int r = 0; r < 4; ++r) {
        const int h = wave * 64 + mf * 16 + lhi * 4 + r;
        const int t = t0 + tf * 16 + l15;
        out[((size_t)(b * H + h)) * T + t] = acc[mf][tf][r];
      }
    }
  }
}

extern "C" void kernel_launch(void* const* d_in, const int* in_sizes, int n_in,
                              void* d_out, int out_size, void* d_ws, size_t ws_size,
                              hipStream_t stream) {
  const float* enc  = (const float*)d_in[0];
  const float* dur  = (const float*)d_in[1];
  const float* vars = (const float*)d_in[2];
  const int*   lens = (const int*)d_in[3];
  float* out = (float*)d_out;

  float*  cbuf  = (float*)d_ws;              // B*N
  float*  a2buf = cbuf + B * N;              // B*N
  float*  q2buf = a2buf + B * N;             // B*N
  float2* msbuf = (float2*)(q2buf + B * N);  // B*T float2

  k_prep<<<B, 64, 0, stream>>>(dur, vars, cbuf, a2buf, q2buf);
  k_ms<<<(B * T) / 4, 256, 0, stream>>>(cbuf, a2buf, q2buf, lens, msbuf);
  k_gemm<<<dim3(T / TTILE, B), 256, 0, stream>>>(enc, cbuf, a2buf, q2buf, lens, msbuf, out);
}

// Round 3
// 79.105 us; speedup vs baseline: 3.4648x; 1.3554x over previous
//
#include <hip/hip_runtime.h>
#include <math.h>
#include <stdint.h>

static constexpr int B = 32, H = 256, N = 512, T = 2048;
static constexpr int TTILE = 64;   // t-tile per gemm block
static constexpr int KC = 64;      // n-chunk
static constexpr int NCHUNK = N / KC;   // 8
static constexpr float kLOG_2PI = 1.8378770664093453f;
static constexpr float kLOG2E   = 1.4426950408889634f;
static constexpr float kNEG_BIG = -3.0e38f;
static constexpr float kRANGE_DELTA = 26.0f;  // log2 threshold below max

typedef __attribute__((ext_vector_type(8))) short bf16x8;
typedef __attribute__((ext_vector_type(4))) float f32x4;

static __device__ __forceinline__ short f2bf(float f) {
  unsigned u = __float_as_uint(f);
  unsigned r = (u + 0x7fffu + ((u >> 16) & 1u)) >> 16;   // RNE
  return (short)r;
}

static __device__ __forceinline__ void gload_lds16(const void* g, void* l) {
  __builtin_amdgcn_global_load_lds(
      (const __attribute__((address_space(1))) unsigned int*)g,
      (__attribute__((address_space(3))) unsigned int*)l, 16, 0, 0);
}

// Kernel 1: per-batch centers c[n] = cumsum(d) - 0.5*d + folded base-2 coeffs:
// w2(n,t) = a2[n] - q2[n]*(t-c[n])^2
__global__ void k_prep(const float* __restrict__ dur, const float* __restrict__ vars,
                       float* __restrict__ c, float* __restrict__ a2, float* __restrict__ q2) {
  const int b = blockIdx.x;
  const int lane = threadIdx.x;  // 64
  float running = 0.f;
  for (int i = 0; i < N / 64; ++i) {
    const int n = i * 64 + lane;
    const float d = dur[b * N + n];
    float x = d;
#pragma unroll
    for (int off = 1; off < 64; off <<= 1) {
      float up = __shfl_up(x, off, 64);
      if (lane >= off) x += up;
    }
    const float cc = running + x - 0.5f * d;
    running += __shfl(x, 63, 64);
    const float v = vars[b * N + n];
    c[b * N + n]  = cc;
    a2[b * N + n] = -0.5f * (kLOG_2PI + logf(v)) * kLOG2E;
    q2[b * N + n] = 0.5f * kLOG2E / v;
  }
}

// Kernel 2: convert enc fp32 -> bf16, stored as pre-swizzled 32KB chunk images
// so k_gemm can global_load_lds them linearly. Image layout (per b, chunk cc):
// byte ((h*KC + k)*2) ^ ((h&7)<<4)  <- enc[b][h][cc*KC + k]
__global__ __launch_bounds__(256) void k_enc_cvt(const float* __restrict__ enc,
                                                 short* __restrict__ encbf) {
  const int cc = blockIdx.x;
  const int b = blockIdx.y;
  const int tid = threadIdx.x;
  const float* encb = enc + (size_t)b * H * N + cc * KC;
  char* img = (char*)encbf + ((size_t)(b * NCHUNK + cc)) * (H * KC * 2);
#pragma unroll
  for (int i = 0; i < 8; ++i) {
    const int flat = i * 256 + tid;        // h*8 + j8
    const int h = flat >> 3, j8 = flat & 7;
    const float4 v0 = *(const float4*)(encb + h * N + j8 * 8);
    const float4 v1 = *(const float4*)(encb + h * N + j8 * 8 + 4);
    bf16x8 w;
    w[0] = f2bf(v0.x); w[1] = f2bf(v0.y); w[2] = f2bf(v0.z); w[3] = f2bf(v0.w);
    w[4] = f2bf(v1.x); w[5] = f2bf(v1.y); w[6] = f2bf(v1.z); w[7] = f2bf(v1.w);
    const int byte = ((h * KC + j8 * 8) * 2) ^ ((h & 7) << 4);
    *(bf16x8*)(img + byte) = w;
  }
}

// Kernel 3: per-(b,t) softmax max m & inv-sum (base-2) + contributing n-range
// [lo,hi] = {n : w2 >= m - DELTA}. Block = (b, 64 t's); 4 threads per t.
__global__ __launch_bounds__(256) void k_msr(
    const float* __restrict__ c, const float* __restrict__ a2,
    const float* __restrict__ q2, const int* __restrict__ lens,
    float2* __restrict__ ms, int2* __restrict__ rng) {
  __shared__ float cs[N], a2s[N], q2s[N];
  const int b = blockIdx.y;
  const int t0 = blockIdx.x * 64;
  const int tid = threadIdx.x;
  for (int i = tid; i < N; i += 256) {
    cs[i] = c[b * N + i]; a2s[i] = a2[b * N + i]; q2s[i] = q2[b * N + i];
  }
  __syncthreads();
  const int L = lens[b];
  const int tl = tid >> 2, j = tid & 3;
  const float tf = (float)(t0 + tl);
  float m = kNEG_BIG;
  for (int i = 0; i < 128; ++i) {
    const int n = j * 128 + i;
    const float tc = tf - cs[n];
    float ww = fmaf(-q2s[n], tc * tc, a2s[n]);
    ww = (n < L) ? ww : kNEG_BIG;
    m = fmaxf(m, ww);
  }
  m = fmaxf(m, __shfl_xor(m, 1, 64));
  m = fmaxf(m, __shfl_xor(m, 2, 64));
  const float thr = m - kRANGE_DELTA;
  float s = 0.f; int lo = N, hi = -1;
  for (int i = 0; i < 128; ++i) {
    const int n = j * 128 + i;
    if (n < L) {
      const float tc = tf - cs[n];
      const float ww = fmaf(-q2s[n], tc * tc, a2s[n]);
      s += exp2f(ww - m);
      if (ww >= thr) { lo = min(lo, n); hi = max(hi, n); }
    }
  }
  s += __shfl_xor(s, 1, 64); s += __shfl_xor(s, 2, 64);
  lo = min(lo, __shfl_xor(lo, 1, 64)); lo = min(lo, __shfl_xor(lo, 2, 64));
  hi = max(hi, __shfl_xor(hi, 1, 64)); hi = max(hi, __shfl_xor(hi, 2, 64));
  if (j == 0) {
    ms[b * T + t0 + tl] = make_float2(m, 1.0f / s);
    rng[b * T + t0 + tl] = make_int2(lo, hi);
  }
}

// Kernel 4: out[b,h,t0+t] = sum_n p(b,n,t)*enc[b,h,n] via bf16 MFMA, but only
// over the K-chunks covering the tile's contributing n-range.
__global__ __launch_bounds__(256) void k_gemm(
    const short* __restrict__ encbf, const float* __restrict__ c,
    const float* __restrict__ a2, const float* __restrict__ q2,
    const int* __restrict__ lens, const float2* __restrict__ ms,
    const int2* __restrict__ rng, float* __restrict__ out) {
  __shared__ short eA[H * KC];       // bf16, swizzled [h][k] (DMA image)
  __shared__ short pB[TTILE * KC];   // bf16, swizzled [t][k]
  __shared__ int sh[4];              // c0, c1, lo, hi

  const int b = blockIdx.y;
  const int t0 = blockIdx.x * TTILE;
  const int tid = threadIdx.x;
  const int lane = tid & 63;
  const int wave = tid >> 6;
  const int L = lens[b];

  // reduce the tile's n-range from per-t ranges
  if (tid < 64) {
    const int2 r = rng[b * T + t0 + tid];
    int lo = r.x, hi = r.y;
#pragma unroll
    for (int off = 32; off; off >>= 1) {
      lo = min(lo, __shfl_xor(lo, off, 64));
      hi = max(hi, __shfl_xor(hi, off, 64));
    }
    if (tid == 0) {
      lo = max(0, min(lo, N - 1)); hi = max(lo, min(hi, N - 1));
      sh[0] = lo >> 6; sh[1] = hi >> 6; sh[2] = lo; sh[3] = hi;
    }
  }

  f32x4 acc[4][4];
#pragma unroll
  for (int mf = 0; mf < 4; ++mf)
#pragma unroll
    for (int tf = 0; tf < 4; ++tf) acc[mf][tf] = (f32x4){0.f, 0.f, 0.f, 0.f};

  __syncthreads();
  const int c0 = sh[0], c1 = sh[1], nlo = sh[2], nhi = sh[3];

  const int l15 = lane & 15;
  const int lhi = lane >> 4;

  for (int cc = c0; cc <= c1; ++cc) {
    const int n0 = cc * KC;
    __syncthreads();   // previous chunk's MFMA reads done (no-op first iter)
    // stage A via async DMA: 32 KB = 8 issues/thread, 1 KB per wave-segment
    const char* srcbase = (const char*)encbf + ((size_t)(b * NCHUNK + cc)) * (H * KC * 2);
#pragma unroll
    for (int i = 0; i < 8; ++i) {
      const int seg = i * 4 + wave;  // wave-uniform
      gload_lds16(srcbase + seg * 1024 + lane * 16, (char*)eA + seg * 1024);
    }
    // stage B: p[t][k], 64x64 bf16; thread handles 2 slots of 8 n's
#pragma unroll
    for (int i = 0; i < 2; ++i) {
      const int flat = i * 256 + tid;       // t*8 + j8
      const int t = flat >> 3, j8 = flat & 7;
      const int nbase = n0 + j8 * 8;
      const int byte = ((t * KC + j8 * 8) * 2) ^ ((t & 7) << 4);
      bf16x8 w;
      if (nbase + 7 < nlo || nbase > nhi) {
        w = (bf16x8){0, 0, 0, 0, 0, 0, 0, 0};
      } else {
        const float2 msv = ms[b * T + t0 + t];
        const float tf = (float)(t0 + t);
#pragma unroll
        for (int jj = 0; jj < 8; ++jj) {
          const int n = nbase + jj;
          const float tc = tf - c[b * N + n];
          const float w2 = fmaf(-q2[b * N + n], tc * tc, a2[b * N + n]);
          const float pv = (n < L) ? exp2f(w2 - msv.x) * msv.y : 0.f;
          w[jj] = f2bf(pv);
        }
      }
      *(bf16x8*)((char*)pB + byte) = w;
    }
    __syncthreads();  // drains vmcnt (DMA) + lgkmcnt
    // MFMA: 2 k-steps of 32, skip steps outside the n-range
#pragma unroll
    for (int kk = 0; kk < KC; kk += 32) {
      if (n0 + kk > nhi || n0 + kk + 31 < nlo) continue;
      bf16x8 aF[4], bF[4];
#pragma unroll
      for (int mf = 0; mf < 4; ++mf) {
        const int h = wave * 64 + mf * 16 + l15;
        const int byte = ((h * KC + kk + lhi * 8) * 2) ^ ((h & 7) << 4);
        aF[mf] = *(const bf16x8*)((const char*)eA + byte);
      }
#pragma unroll
      for (int tf = 0; tf < 4; ++tf) {
        const int t = tf * 16 + l15;
        const int byte = ((t * KC + kk + lhi * 8) * 2) ^ ((t & 7) << 4);
        bF[tf] = *(const bf16x8*)((const char*)pB + byte);
      }
#pragma unroll
      for (int mf = 0; mf < 4; ++mf)
#pragma unroll
        for (int tf = 0; tf < 4; ++tf)
          acc[mf][tf] = __builtin_amdgcn_mfma_f32_16x16x32_bf16(aF[mf], bF[tf], acc[mf][tf], 0, 0, 0);
    }
  }

  // epilogue: C/D layout col(t)=lane&15, row(h)=(lane>>4)*4+r
#pragma unroll
  for (int mf = 0; mf < 4; ++mf) {
#pragma unroll
    for (int tf = 0; tf < 4; ++tf) {
#pragma unroll
      for (int r = 0; r < 4; ++r) {
        const int h = wave * 64 + mf * 16 + lhi * 4 + r;
        const int t = t0 + tf * 16 + l15;
        out[((size_t)(b * H + h)) * T + t] = acc[mf][tf][r];
      }
    }
  }
}

extern "C" void kernel_launch(void* const* d_in, const int* in_sizes, int n_in,
                              void* d_out, int out_size, void* d_ws, size_t ws_size,
                              hipStream_t stream) {
  const float* enc  = (const float*)d_in[0];
  const float* dur  = (const float*)d_in[1];
  const float* vars = (const float*)d_in[2];
  const int*   lens = (const int*)d_in[3];
  float* out = (float*)d_out;

  char* ws = (char*)d_ws;
  float*  cbuf   = (float*)ws;                          // B*N
  float*  a2buf  = cbuf + B * N;                        // B*N
  float*  q2buf  = a2buf + B * N;                       // B*N
  float2* msbuf  = (float2*)(q2buf + B * N);            // B*T
  int2*   rngbuf = (int2*)(msbuf + B * T);              // B*T
  short*  encbf  = (short*)(rngbuf + B * T);            // B*H*N bf16 (8.4 MB)

  k_prep<<<B, 64, 0, stream>>>(dur, vars, cbuf, a2buf, q2buf);
  k_enc_cvt<<<dim3(NCHUNK, B), 256, 0, stream>>>(enc, encbf);
  k_msr<<<dim3(T / 64, B), 256, 0, stream>>>(cbuf, a2buf, q2buf, lens, msbuf, rngbuf);
  k_gemm<<<dim3(T / TTILE, B), 256, 0, stream>>>(encbf, cbuf, a2buf, q2buf, lens, msbuf, rngbuf, out);
}

// Round 4
// 46.116 us; speedup vs baseline: 5.9433x; 1.7153x over previous
//
#include <hip/hip_runtime.h>
#include <math.h>
#include <stdint.h>

static constexpr int B = 32, H = 256, N = 512, T = 2048;
static constexpr int TTILE = 64;   // t-tile per fused block
static constexpr int KC = 64;      // n-chunk
static constexpr int NCHUNK = N / KC;   // 8
static constexpr float kLOG_2PI = 1.8378770664093453f;
static constexpr float kLOG2E   = 1.4426950408889634f;
static constexpr float kNEG_BIG = -3.0e38f;
static constexpr float kRANGE_DELTA = 26.0f;  // log2 threshold below max

typedef __attribute__((ext_vector_type(8))) short bf16x8;
typedef __attribute__((ext_vector_type(4))) float f32x4;

static __device__ __forceinline__ short f2bf(float f) {
  unsigned u = __float_as_uint(f);
  unsigned r = (u + 0x7fffu + ((u >> 16) & 1u)) >> 16;   // RNE
  return (short)r;
}

static __device__ __forceinline__ void gload_lds16(const void* g, void* l) {
  __builtin_amdgcn_global_load_lds(
      (const __attribute__((address_space(1))) unsigned int*)g,
      (__attribute__((address_space(3))) unsigned int*)l, 16, 0, 0);
}

// Kernel 1: per-batch centers c[n] = cumsum(d) - 0.5*d + folded base-2 coeffs:
// w2(n,t) = a2[n] - q2[n]*(t-c[n])^2
__global__ void k_prep(const float* __restrict__ dur, const float* __restrict__ vars,
                       float* __restrict__ c, float* __restrict__ a2, float* __restrict__ q2) {
  const int b = blockIdx.x;
  const int lane = threadIdx.x;  // 64
  float running = 0.f;
  for (int i = 0; i < N / 64; ++i) {
    const int n = i * 64 + lane;
    const float d = dur[b * N + n];
    float x = d;
#pragma unroll
    for (int off = 1; off < 64; off <<= 1) {
      float up = __shfl_up(x, off, 64);
      if (lane >= off) x += up;
    }
    const float cc = running + x - 0.5f * d;
    running += __shfl(x, 63, 64);
    const float v = vars[b * N + n];
    c[b * N + n]  = cc;
    a2[b * N + n] = -0.5f * (kLOG_2PI + logf(v)) * kLOG2E;
    q2[b * N + n] = 0.5f * kLOG2E / v;
  }
}

// Kernel 2: convert enc fp32 -> bf16 pre-swizzled 32KB chunk images for
// linear global_load_lds. byte ((h*KC+k)*2)^((h&7)<<4) <- enc[b][h][cc*KC+k].
// Chunks entirely in the masked region (n0 >= L) are never read -> skip.
__global__ __launch_bounds__(256) void k_enc_cvt(const float* __restrict__ enc,
                                                 const int* __restrict__ lens,
                                                 short* __restrict__ encbf) {
  const int cc = blockIdx.x;
  const int b = blockIdx.y;
  if (cc * KC >= lens[b]) return;
  const int tid = threadIdx.x;
  const float* encb = enc + (size_t)b * H * N + cc * KC;
  char* img = (char*)encbf + ((size_t)(b * NCHUNK + cc)) * (H * KC * 2);
#pragma unroll
  for (int i = 0; i < 8; ++i) {
    const int flat = i * 256 + tid;        // h*8 + j8
    const int h = flat >> 3, j8 = flat & 7;
    const float4 v0 = *(const float4*)(encb + h * N + j8 * 8);
    const float4 v1 = *(const float4*)(encb + h * N + j8 * 8 + 4);
    bf16x8 w;
    w[0] = f2bf(v0.x); w[1] = f2bf(v0.y); w[2] = f2bf(v0.z); w[3] = f2bf(v0.w);
    w[4] = f2bf(v1.x); w[5] = f2bf(v1.y); w[6] = f2bf(v1.z); w[7] = f2bf(v1.w);
    const int byte = ((h * KC + j8 * 8) * 2) ^ ((h & 7) << 4);
    *(bf16x8*)(img + byte) = w;
  }
}

// Kernel 3 (fused): per-(b, 64t) block.
// Phase 1: exact per-t max m (n<L), contributing range [lo,hi] (w2 >= m-26).
// Phase 2: chunk loop over [lo>>6, hi>>6]: DMA A image, generate unnormalized
//          p (bf16) + accumulate s[t] in LDS, MFMA accumulate.
// Epilogue: scale by 1/s[t].
__global__ __launch_bounds__(256) void k_fused(
    const short* __restrict__ encbf, const float* __restrict__ c,
    const float* __restrict__ a2, const float* __restrict__ q2,
    const int* __restrict__ lens, float* __restrict__ out) {
  __shared__ short eA[H * KC];       // 32 KB bf16, swizzled [h][k] (DMA image)
  __shared__ short pB[TTILE * KC];   // 8 KB bf16, swizzled [t][k]
  __shared__ float cs[N], a2s[N], q2s[N];   // 6 KB
  __shared__ float m_lds[TTILE];
  __shared__ float s_lds[TTILE];
  __shared__ int range_sh[2];        // block lo, hi

  const int b = blockIdx.y;
  const int t0 = blockIdx.x * TTILE;
  const int tid = threadIdx.x;
  const int lane = tid & 63;
  const int wave = tid >> 6;
  const int L = lens[b];

  for (int i = tid; i < N; i += 256) {
    cs[i] = c[b * N + i]; a2s[i] = a2[b * N + i]; q2s[i] = q2[b * N + i];
  }
  if (tid < TTILE) s_lds[tid] = 0.f;
  if (tid == 0) { range_sh[0] = N; range_sh[1] = -1; }
  __syncthreads();

  // ---- Phase 1: max + range (4 threads per t, n = i*4+j -> conflict-free) ----
  const int tl = tid >> 2, j = tid & 3;
  const float tf = (float)(t0 + tl);
  const int iL = (L + 3) >> 2;
  float mA = kNEG_BIG, mB = kNEG_BIG;
  int i1 = 0;
  for (; i1 + 1 < iL; i1 += 2) {
    const int n1 = i1 * 4 + j, n2 = n1 + 4;
    const float tc1 = tf - cs[n1];
    const float w1 = fmaf(-q2s[n1], tc1 * tc1, a2s[n1]);
    mA = fmaxf(mA, (n1 < L) ? w1 : kNEG_BIG);
    const float tc2 = tf - cs[n2];
    const float w2 = fmaf(-q2s[n2], tc2 * tc2, a2s[n2]);
    mB = fmaxf(mB, (n2 < L) ? w2 : kNEG_BIG);
  }
  if (i1 < iL) {
    const int n1 = i1 * 4 + j;
    const float tc1 = tf - cs[n1];
    const float w1 = fmaf(-q2s[n1], tc1 * tc1, a2s[n1]);
    mA = fmaxf(mA, (n1 < L) ? w1 : kNEG_BIG);
  }
  float m = fmaxf(mA, mB);
  m = fmaxf(m, __shfl_xor(m, 1, 64));
  m = fmaxf(m, __shfl_xor(m, 2, 64));
  if (j == 0) m_lds[tl] = m;

  const float thr = m - kRANGE_DELTA;
  int lo = N, hi = -1;
  for (int i2 = 0; i2 < iL; ++i2) {
    const int n = i2 * 4 + j;
    const float tc = tf - cs[n];
    const float ww = fmaf(-q2s[n], tc * tc, a2s[n]);
    if (n < L && ww >= thr) { lo = min(lo, n); hi = max(hi, n); }
  }
#pragma unroll
  for (int off = 32; off; off >>= 1) {
    lo = min(lo, __shfl_xor(lo, off, 64));
    hi = max(hi, __shfl_xor(hi, off, 64));
  }
  if (lane == 0) { atomicMin(&range_sh[0], lo); atomicMax(&range_sh[1], hi); }
  __syncthreads();

  int nlo = range_sh[0], nhi = range_sh[1];
  nlo = max(0, min(nlo, N - 1)); nhi = max(nlo, min(nhi, N - 1));
  const int c0 = nlo >> 6, c1 = nhi >> 6;

  f32x4 acc[4][4];
#pragma unroll
  for (int mf = 0; mf < 4; ++mf)
#pragma unroll
    for (int tt = 0; tt < 4; ++tt) acc[mf][tt] = (f32x4){0.f, 0.f, 0.f, 0.f};

  const int l15 = lane & 15;
  const int lhi = lane >> 4;

  // ---- Phase 2: chunk loop ----
  for (int cc = c0; cc <= c1; ++cc) {
    const int n0 = cc * KC;
    __syncthreads();   // prev chunk's MFMA reads done
    // stage A via async DMA: 32 KB = 8 issues/thread (1 KB per wave-segment)
    const char* srcbase = (const char*)encbf + ((size_t)(b * NCHUNK + cc)) * (H * KC * 2);
#pragma unroll
    for (int i = 0; i < 8; ++i) {
      const int seg = i * 4 + wave;  // wave-uniform
      gload_lds16(srcbase + seg * 1024 + lane * 16, (char*)eA + seg * 1024);
    }
    // stage B: unnormalized p[t][k] bf16 + s[t] accumulation
#pragma unroll
    for (int i = 0; i < 2; ++i) {
      const int flat = i * 256 + tid;       // t*8 + j8
      const int t = flat >> 3, j8 = flat & 7;
      const int nbase = n0 + j8 * 8;
      const int byte = ((t * KC + j8 * 8) * 2) ^ ((t & 7) << 4);
      const float mt = m_lds[t];
      const float tft = (float)(t0 + t);
      bf16x8 w;
      float psum = 0.f;
#pragma unroll
      for (int jj = 0; jj < 8; ++jj) {
        const int n = nbase + jj;
        const float tc = tft - cs[n];
        const float w2v = fmaf(-q2s[n], tc * tc, a2s[n]);
        const float pv = (n < L) ? exp2f(w2v - mt) : 0.f;
        psum += pv;
        w[jj] = f2bf(pv);
      }
      *(bf16x8*)((char*)pB + byte) = w;
      psum += __shfl_xor(psum, 1, 64);
      psum += __shfl_xor(psum, 2, 64);
      psum += __shfl_xor(psum, 4, 64);
      if ((tid & 7) == 0) atomicAdd(&s_lds[t], psum);
    }
    __syncthreads();  // drains DMA (vmcnt) + LDS writes
    // MFMA: 2 k-steps of 32, skip steps outside the n-range
#pragma unroll
    for (int kk = 0; kk < KC; kk += 32) {
      if (n0 + kk > nhi || n0 + kk + 31 < nlo) continue;
      bf16x8 aF[4], bF[4];
#pragma unroll
      for (int mf = 0; mf < 4; ++mf) {
        const int h = wave * 64 + mf * 16 + l15;
        const int byte = ((h * KC + kk + lhi * 8) * 2) ^ ((h & 7) << 4);
        aF[mf] = *(const bf16x8*)((const char*)eA + byte);
      }
#pragma unroll
      for (int tt = 0; tt < 4; ++tt) {
        const int t = tt * 16 + l15;
        const int byte = ((t * KC + kk + lhi * 8) * 2) ^ ((t & 7) << 4);
        bF[tt] = *(const bf16x8*)((const char*)pB + byte);
      }
#pragma unroll
      for (int mf = 0; mf < 4; ++mf)
#pragma unroll
        for (int tt = 0; tt < 4; ++tt)
          acc[mf][tt] = __builtin_amdgcn_mfma_f32_16x16x32_bf16(aF[mf], bF[tt], acc[mf][tt], 0, 0, 0);
    }
  }

  // ---- Epilogue: normalize by 1/s[t]; C/D layout col(t)=lane&15, row=(lane>>4)*4+r
#pragma unroll
  for (int tt = 0; tt < 4; ++tt) {
    const int t = tt * 16 + l15;
    const float is = 1.0f / s_lds[t];
#pragma unroll
    for (int mf = 0; mf < 4; ++mf) {
#pragma unroll
      for (int r = 0; r < 4; ++r) {
        const int h = wave * 64 + mf * 16 + lhi * 4 + r;
        out[((size_t)(b * H + h)) * T + t0 + t] = acc[mf][tt][r] * is;
      }
    }
  }
}

extern "C" void kernel_launch(void* const* d_in, const int* in_sizes, int n_in,
                              void* d_out, int out_size, void* d_ws, size_t ws_size,
                              hipStream_t stream) {
  const float* enc  = (const float*)d_in[0];
  const float* dur  = (const float*)d_in[1];
  const float* vars = (const float*)d_in[2];
  const int*   lens = (const int*)d_in[3];
  float* out = (float*)d_out;

  char* ws = (char*)d_ws;
  float* cbuf  = (float*)ws;             // B*N
  float* a2buf = cbuf + B * N;           // B*N
  float* q2buf = a2buf + B * N;          // B*N
  short* encbf = (short*)(q2buf + B * N);  // B*H*N bf16 (8.4 MB), 16B-aligned

  k_prep<<<B, 64, 0, stream>>>(dur, vars, cbuf, a2buf, q2buf);
  k_enc_cvt<<<dim3(NCHUNK, B), 256, 0, stream>>>(enc, lens, encbf);
  k_fused<<<dim3(T / TTILE, B), 256, 0, stream>>>(encbf, cbuf, a2buf, q2buf, lens, out);
}